// Round 9
// baseline (1371.282 us; speedup 1.0000x reference)
//
#include <hip/hip_runtime.h>
#include <hip/hip_bf16.h>
#include <stdint.h>

typedef __attribute__((ext_vector_type(8))) short bf16x8;
typedef __attribute__((ext_vector_type(4))) float f32x4;

__device__ __forceinline__ uint16_t f2bf(float f) {
  uint32_t u = __builtin_bit_cast(uint32_t, f);
  u += 0x7fffu + ((u >> 16) & 1u);   // round-to-nearest-even
  return (uint16_t)(u >> 16);
}

// ---------------- fp32 -> bf16 conversion (vectorized, grid-stride) ----------
__global__ __launch_bounds__(256) void cvt_bf16(const float* __restrict__ in,
                                                uint16_t* __restrict__ out,
                                                size_t n8) {
  size_t i = (size_t)blockIdx.x * blockDim.x + threadIdx.x;
  size_t stride = (size_t)gridDim.x * blockDim.x;
  for (; i < n8; i += stride) {
    const float4* p = reinterpret_cast<const float4*>(in) + 2 * i;
    float4 a = p[0], b = p[1];
    uint4 o;
    o.x = (uint32_t)f2bf(a.x) | ((uint32_t)f2bf(a.y) << 16);
    o.y = (uint32_t)f2bf(a.z) | ((uint32_t)f2bf(a.w) << 16);
    o.z = (uint32_t)f2bf(b.x) | ((uint32_t)f2bf(b.y) << 16);
    o.w = (uint32_t)f2bf(b.z) | ((uint32_t)f2bf(b.w) << 16);
    reinterpret_cast<uint4*>(out)[i] = o;
  }
}

// Same, but output has extra zero rows at the end (pad V=30000 -> 30080).
// K is fixed at 2048 (shift 11).
__global__ __launch_bounds__(256) void cvt_bf16_pad(const float* __restrict__ in,
                                                    uint16_t* __restrict__ out,
                                                    int rows_in, size_t n8) {
  size_t i = (size_t)blockIdx.x * blockDim.x + threadIdx.x;
  size_t stride = (size_t)gridDim.x * blockDim.x;
  for (; i < n8; i += stride) {
    size_t row = (i * 8) >> 11;
    uint4 o;
    if (row < (size_t)rows_in) {
      const float4* p = reinterpret_cast<const float4*>(in) + 2 * i;
      float4 a = p[0], b = p[1];
      o.x = (uint32_t)f2bf(a.x) | ((uint32_t)f2bf(a.y) << 16);
      o.y = (uint32_t)f2bf(a.z) | ((uint32_t)f2bf(a.w) << 16);
      o.z = (uint32_t)f2bf(b.x) | ((uint32_t)f2bf(b.y) << 16);
      o.w = (uint32_t)f2bf(b.z) | ((uint32_t)f2bf(b.w) << 16);
    } else {
      o.x = 0u; o.y = 0u; o.z = 0u; o.w = 0u;
    }
    reinterpret_cast<uint4*>(out)[i] = o;
  }
}

// ---------------- bf16 GEMM, C = A @ B^T (+bias), m97 128x128 structure -----
// A: [M,K] bf16 row-major; B: [Npad,K] bf16 row-major; C: [M,Nout] fp32.
// Requires M%128==0, Npad%128==0, K%32==0, grid = (M/128)*(Npad/128), nwg%8==0.
// Block mapping: XCD-chunked (contiguous swz per XCD) with tm FASTEST inside
// the chunk -> each XCD streams a narrow band of B-strips, each strip is
// L2-resident and reused by all m-tiles (B fetched ~once from HBM total).
#define GLOAD16(g, l) __builtin_amdgcn_global_load_lds(                         \
    (__attribute__((address_space(1))) const void*)(g),                         \
    (__attribute__((address_space(3))) void*)(l), 16, 0, 0)

__global__ __launch_bounds__(256, 2) void gemm_bt_bf16(
    const uint16_t* __restrict__ A, const uint16_t* __restrict__ B,
    float* __restrict__ C, const float* __restrict__ bias,
    int M, int Npad, int K, int Nout)
{
  constexpr int BM = 128, BN = 128, BK = 32;
  __shared__ uint16_t sA[BM * BK];
  __shared__ uint16_t sB[BN * BK];

  const int ntile = Npad / BN;
  const int mtile = M / BM;
  const int nwg = ntile * mtile;
  const int bid = blockIdx.x;
  // XCD-aware swizzle (bijective since nwg % 8 == 0 for our launches)
  const int cpx = nwg >> 3;
  const int swz = (bid & 7) * cpx + (bid >> 3);
  // m-fastest within the XCD chunk: B-strip (tn) changes every mtile blocks
  const int tm = swz % mtile;
  const int tn = swz / mtile;

  const int tid = threadIdx.x;
  const int lane = tid & 63;
  const int wid = tid >> 6;
  const int wm = wid >> 1;   // 2x2 wave grid, each wave owns 64x64 of C
  const int wn = wid & 1;

  // staging: thread t loads 16B (8 bf16) from row (t>>2), k-offset (t&3)*8
  const int srow = tid >> 2;
  const int scol = (tid & 3) * 8;
  const uint16_t* ga0 = A + (size_t)(tm * BM + srow) * K + scol;
  const uint16_t* ga1 = ga0 + (size_t)64 * K;
  const uint16_t* gb0 = B + (size_t)(tn * BN + srow) * K + scol;
  const uint16_t* gb1 = gb0 + (size_t)64 * K;
  uint16_t* lA = sA + wid * 512;   // wave-uniform LDS dest (1024B per wave)
  uint16_t* lB = sB + wid * 512;

  // MFMA fragment addresses: A row = lane&15 (+m*16), k-block = lane>>4
  const int arow = wm * 64 + (lane & 15);
  const int brow = wn * 64 + (lane & 15);
  const int koff = (lane >> 4) * 8;

  f32x4 acc[4][4];
  #pragma unroll
  for (int m = 0; m < 4; ++m)
    #pragma unroll
    for (int n = 0; n < 4; ++n)
      acc[m][n] = (f32x4){0.f, 0.f, 0.f, 0.f};

  for (int k0 = 0; k0 < K; k0 += BK) {
    __syncthreads();                 // previous tile's reads done
    GLOAD16(ga0, lA);
    GLOAD16(ga1, lA + 2048);
    GLOAD16(gb0, lB);
    GLOAD16(gb1, lB + 2048);
    ga0 += BK; ga1 += BK; gb0 += BK; gb1 += BK;
    __syncthreads();                 // vmcnt(0) drain: tile landed

    bf16x8 af[4], bfr[4];
    #pragma unroll
    for (int m = 0; m < 4; ++m)
      af[m] = *reinterpret_cast<const bf16x8*>(&sA[(arow + m * 16) * BK + koff]);
    #pragma unroll
    for (int n = 0; n < 4; ++n)
      bfr[n] = *reinterpret_cast<const bf16x8*>(&sB[(brow + n * 16) * BK + koff]);
    #pragma unroll
    for (int m = 0; m < 4; ++m)
      #pragma unroll
      for (int n = 0; n < 4; ++n)
        acc[m][n] = __builtin_amdgcn_mfma_f32_16x16x32_bf16(af[m], bfr[n],
                                                            acc[m][n], 0, 0, 0);
  }

  // epilogue: D row = (lane>>4)*4 + j, col = lane&15 (m89-verified layout)
  const int r0 = tm * BM + wm * 64 + (lane >> 4) * 4;
  const int c0 = tn * BN + wn * 64 + (lane & 15);
  #pragma unroll
  for (int m = 0; m < 4; ++m) {
    #pragma unroll
    for (int n = 0; n < 4; ++n) {
      const int c = c0 + n * 16;
      if (c < Nout) {
        const float bv = bias ? bias[c] : 0.f;
        #pragma unroll
        for (int j = 0; j < 4; ++j)
          C[(size_t)(r0 + m * 16 + j) * Nout + c] = acc[m][n][j] + bv;
      }
    }
  }
}

// ---------------- LayerNorm (adds b1), fp32 in -> bf16 out ------------------
__global__ __launch_bounds__(256) void ln_bf16(
    const float* __restrict__ h, const float* __restrict__ b1,
    const float* __restrict__ gamma, const float* __restrict__ beta,
    uint16_t* __restrict__ out)
{
  constexpr int D = 2048;
  const int row = blockIdx.x;
  const int tid = threadIdx.x;
  const float* hp = h + (size_t)row * D + tid * 8;
  float v[8];
  {
    float4 a0 = *reinterpret_cast<const float4*>(hp);
    float4 a1 = *reinterpret_cast<const float4*>(hp + 4);
    float4 c0 = *reinterpret_cast<const float4*>(b1 + tid * 8);
    float4 c1 = *reinterpret_cast<const float4*>(b1 + tid * 8 + 4);
    v[0] = a0.x + c0.x; v[1] = a0.y + c0.y; v[2] = a0.z + c0.z; v[3] = a0.w + c0.w;
    v[4] = a1.x + c1.x; v[5] = a1.y + c1.y; v[6] = a1.z + c1.z; v[7] = a1.w + c1.w;
  }
  float s = 0.f, q = 0.f;
  #pragma unroll
  for (int i = 0; i < 8; ++i) { s += v[i]; q += v[i] * v[i]; }
  #pragma unroll
  for (int off = 32; off > 0; off >>= 1) {
    s += __shfl_down(s, off);
    q += __shfl_down(q, off);
  }
  __shared__ float red[8];
  const int wid = tid >> 6, lane = tid & 63;
  if (lane == 0) { red[wid] = s; red[4 + wid] = q; }
  __syncthreads();
  s = red[0] + red[1] + red[2] + red[3];
  q = red[4] + red[5] + red[6] + red[7];
  const float mu = s * (1.f / D);
  const float rs = rsqrtf(q * (1.f / D) - mu * mu + 1e-5f);
  float4 g0 = *reinterpret_cast<const float4*>(gamma + tid * 8);
  float4 g1 = *reinterpret_cast<const float4*>(gamma + tid * 8 + 4);
  float4 e0 = *reinterpret_cast<const float4*>(beta + tid * 8);
  float4 e1 = *reinterpret_cast<const float4*>(beta + tid * 8 + 4);
  const float g[8] = {g0.x, g0.y, g0.z, g0.w, g1.x, g1.y, g1.z, g1.w};
  const float e[8] = {e0.x, e0.y, e0.z, e0.w, e1.x, e1.y, e1.z, e1.w};
  uint32_t w[4];
  #pragma unroll
  for (int i = 0; i < 4; ++i) {
    float y0 = (v[2 * i]     - mu) * rs * g[2 * i]     + e[2 * i];
    float y1 = (v[2 * i + 1] - mu) * rs * g[2 * i + 1] + e[2 * i + 1];
    w[i] = (uint32_t)f2bf(y0) | ((uint32_t)f2bf(y1) << 16);
  }
  uint4 o; o.x = w[0]; o.y = w[1]; o.z = w[2]; o.w = w[3];
  reinterpret_cast<uint4*>(out + (size_t)row * D)[tid] = o;
}

// ---------------- launch ----------------------------------------------------
extern "C" void kernel_launch(void* const* d_in, const int* in_sizes, int n_in,
                              void* d_out, int out_size, void* d_ws, size_t ws_size,
                              hipStream_t stream) {
  (void)in_sizes; (void)n_in; (void)out_size; (void)ws_size;
  const float* x     = (const float*)d_in[0];
  const float* w1    = (const float*)d_in[1];
  const float* b1    = (const float*)d_in[2];
  const float* gamma = (const float*)d_in[3];
  const float* beta  = (const float*)d_in[4];
  const float* w3    = (const float*)d_in[5];
  const float* b3    = (const float*)d_in[6];
  float* out = (float*)d_out;

  const int N = 4096, D = 2048, V = 30000, Vp = 30080;

  char* ws = (char*)d_ws;
  uint16_t* xb  = (uint16_t*)(ws);                    // 16 MiB: x bf16
  uint16_t* w1b = (uint16_t*)(ws + (16u  << 20));     //  8 MiB: w1 bf16
  float*    h   = (float*)   (ws + (24u  << 20));     // 32 MiB: h fp32
  uint16_t* hnb = (uint16_t*)(ws + (56u  << 20));     // 16 MiB: hn bf16
  uint16_t* w3b = (uint16_t*)(ws + (72u  << 20));     // 117.5 MiB: w3 bf16 padded

  hipLaunchKernelGGL(cvt_bf16, dim3(1024), dim3(256), 0, stream,
                     x, xb, (size_t)N * D / 8);
  hipLaunchKernelGGL(cvt_bf16, dim3(512), dim3(256), 0, stream,
                     w1, w1b, (size_t)D * D / 8);
  hipLaunchKernelGGL(cvt_bf16_pad, dim3(2048), dim3(256), 0, stream,
                     w3, w3b, V, (size_t)Vp * D / 8);
  // GEMM1: h = x @ w1^T  (b1 folded into LN)
  hipLaunchKernelGGL(gemm_bt_bf16, dim3((N / 128) * (D / 128)), dim3(256), 0, stream,
                     xb, w1b, h, (const float*)nullptr, N, D, D, D);
  hipLaunchKernelGGL(ln_bf16, dim3(N), dim3(256), 0, stream,
                     h, b1, gamma, beta, hnb);
  // GEMM2: out = hn @ w3^T + b3
  hipLaunchKernelGGL(gemm_bt_bf16, dim3((N / 128) * (Vp / 128)), dim3(256), 0, stream,
                     hnb, w3b, out, b3, N, Vp, D, V);
}

// Round 11
// 1264.407 us; speedup vs baseline: 1.0845x; 1.0845x over previous
//
#include <hip/hip_runtime.h>
#include <hip/hip_bf16.h>
#include <stdint.h>

typedef __attribute__((ext_vector_type(8))) short bf16x8;
typedef __attribute__((ext_vector_type(4))) float f32x4;

__device__ __forceinline__ uint16_t f2bf(float f) {
  uint32_t u = __builtin_bit_cast(uint32_t, f);
  u += 0x7fffu + ((u >> 16) & 1u);   // round-to-nearest-even
  return (uint16_t)(u >> 16);
}

// ---------------- fp32 -> bf16 conversion (vectorized, grid-stride) ----------
__global__ __launch_bounds__(256) void cvt_bf16(const float* __restrict__ in,
                                                uint16_t* __restrict__ out,
                                                size_t n8) {
  size_t i = (size_t)blockIdx.x * blockDim.x + threadIdx.x;
  size_t stride = (size_t)gridDim.x * blockDim.x;
  for (; i < n8; i += stride) {
    const float4* p = reinterpret_cast<const float4*>(in) + 2 * i;
    float4 a = p[0], b = p[1];
    uint4 o;
    o.x = (uint32_t)f2bf(a.x) | ((uint32_t)f2bf(a.y) << 16);
    o.y = (uint32_t)f2bf(a.z) | ((uint32_t)f2bf(a.w) << 16);
    o.z = (uint32_t)f2bf(b.x) | ((uint32_t)f2bf(b.y) << 16);
    o.w = (uint32_t)f2bf(b.z) | ((uint32_t)f2bf(b.w) << 16);
    reinterpret_cast<uint4*>(out)[i] = o;
  }
}

// Pad V rows -> Vp rows with zeros. K fixed at 2048 (shift 11).
__global__ __launch_bounds__(256) void cvt_bf16_pad(const float* __restrict__ in,
                                                    uint16_t* __restrict__ out,
                                                    int rows_in, size_t n8) {
  size_t i = (size_t)blockIdx.x * blockDim.x + threadIdx.x;
  size_t stride = (size_t)gridDim.x * blockDim.x;
  for (; i < n8; i += stride) {
    size_t row = (i * 8) >> 11;
    uint4 o;
    if (row < (size_t)rows_in) {
      const float4* p = reinterpret_cast<const float4*>(in) + 2 * i;
      float4 a = p[0], b = p[1];
      o.x = (uint32_t)f2bf(a.x) | ((uint32_t)f2bf(a.y) << 16);
      o.y = (uint32_t)f2bf(a.z) | ((uint32_t)f2bf(a.w) << 16);
      o.z = (uint32_t)f2bf(b.x) | ((uint32_t)f2bf(b.y) << 16);
      o.w = (uint32_t)f2bf(b.z) | ((uint32_t)f2bf(b.w) << 16);
    } else {
      o.x = 0u; o.y = 0u; o.z = 0u; o.w = 0u;
    }
    reinterpret_cast<uint4*>(out)[i] = o;
  }
}

#define GLOAD16(g, l) __builtin_amdgcn_global_load_lds(                         \
    (__attribute__((address_space(1))) const void*)(g),                         \
    (__attribute__((address_space(3))) void*)(l), 16, 0, 0)

// ---------------- OLD 128x128 kernel (kept for GEMM1, known-good) -----------
__global__ __launch_bounds__(256, 2) void gemm_bt_bf16(
    const uint16_t* __restrict__ A, const uint16_t* __restrict__ B,
    float* __restrict__ C, const float* __restrict__ bias,
    int M, int Npad, int K, int Nout)
{
  constexpr int BM = 128, BN = 128, BK = 32;
  __shared__ uint16_t sA[BM * BK];
  __shared__ uint16_t sB[BN * BK];

  const int ntile = Npad / BN;
  const int mtile = M / BM;
  const int nwg = ntile * mtile;
  const int bid = blockIdx.x;
  const int cpx = nwg >> 3;
  const int swz = (bid & 7) * cpx + (bid >> 3);
  const int tm = swz % mtile;
  const int tn = swz / mtile;

  const int tid = threadIdx.x;
  const int lane = tid & 63;
  const int wid = tid >> 6;
  const int wm = wid >> 1;
  const int wn = wid & 1;

  const int srow = tid >> 2;
  const int scol = (tid & 3) * 8;
  const uint16_t* ga0 = A + (size_t)(tm * BM + srow) * K + scol;
  const uint16_t* ga1 = ga0 + (size_t)64 * K;
  const uint16_t* gb0 = B + (size_t)(tn * BN + srow) * K + scol;
  const uint16_t* gb1 = gb0 + (size_t)64 * K;
  uint16_t* lA = sA + wid * 512;
  uint16_t* lB = sB + wid * 512;

  const int arow = wm * 64 + (lane & 15);
  const int brow = wn * 64 + (lane & 15);
  const int koff = (lane >> 4) * 8;

  f32x4 acc[4][4];
  #pragma unroll
  for (int m = 0; m < 4; ++m)
    #pragma unroll
    for (int n = 0; n < 4; ++n)
      acc[m][n] = (f32x4){0.f, 0.f, 0.f, 0.f};

  for (int k0 = 0; k0 < K; k0 += BK) {
    __syncthreads();
    GLOAD16(ga0, lA);
    GLOAD16(ga1, lA + 2048);
    GLOAD16(gb0, lB);
    GLOAD16(gb1, lB + 2048);
    ga0 += BK; ga1 += BK; gb0 += BK; gb1 += BK;
    __syncthreads();

    bf16x8 af[4], bfr[4];
    #pragma unroll
    for (int m = 0; m < 4; ++m)
      af[m] = *reinterpret_cast<const bf16x8*>(&sA[(arow + m * 16) * BK + koff]);
    #pragma unroll
    for (int n = 0; n < 4; ++n)
      bfr[n] = *reinterpret_cast<const bf16x8*>(&sB[(brow + n * 16) * BK + koff]);
    #pragma unroll
    for (int m = 0; m < 4; ++m)
      #pragma unroll
      for (int n = 0; n < 4; ++n)
        acc[m][n] = __builtin_amdgcn_mfma_f32_16x16x32_bf16(af[m], bfr[n],
                                                            acc[m][n], 0, 0, 0);
  }

  const int r0 = tm * BM + wm * 64 + (lane >> 4) * 4;
  const int c0 = tn * BN + wn * 64 + (lane & 15);
  #pragma unroll
  for (int m = 0; m < 4; ++m) {
    #pragma unroll
    for (int n = 0; n < 4; ++n) {
      const int c = c0 + n * 16;
      if (c < Nout) {
        const float bv = bias ? bias[c] : 0.f;
        #pragma unroll
        for (int j = 0; j < 4; ++j)
          C[(size_t)(r0 + m * 16 + j) * Nout + c] = acc[m][n][j] + bv;
      }
    }
  }
}

// ---------------- NEW: 256x256 tile, BK=32, 8 waves, ring-4 LDS, counted vmcnt
// STATIC 128 KiB LDS (dynamic >64 KiB risks hipFuncSetAttribute requirement).
// Ledger (race-free):
//   prologue stages tiles 0,1,2 (4 loads each thread).
//   iter t: wait vmcnt(8/4/0) -> own tile-t loads landed; s_barrier -> ALL
//   threads' tile-t loads landed; stage tile t+3 into buf[(t+3)&3] (that buf
//   was last READ at iter t-1; those ds_reads completed before this barrier
//   because their consuming MFMAs executed); ds_read buf[t&3]; 32 MFMA.
//   Steady state: 8-12 loads (2-3 K-tiles) in flight across barriers.
__global__ __launch_bounds__(512, 2) void gemm_bt_256(
    const uint16_t* __restrict__ A, const uint16_t* __restrict__ B,
    float* __restrict__ C, const float* __restrict__ bias,
    int M, int Npad, int K, int Nout)
{
  __shared__ char lds[131072];       // 4 bufs x (A 16K | B 16K)
  constexpr int BM = 256, BN = 256, BK = 32;
  const int ntile = Npad / BN;
  const int mtile = M / BM;
  const int nwg = ntile * mtile;
  const int bid = blockIdx.x;
  const int cpx = nwg >> 3;
  const int swz = (bid & 7) * cpx + (bid >> 3);
  const int tm = swz % mtile;        // m-fastest within XCD chunk
  const int tn = swz / mtile;

  const int tid = threadIdx.x;
  const int lane = tid & 63;
  const int wid = tid >> 6;          // 0..7
  const int wm = wid >> 2;           // 2 M-waves
  const int wn = wid & 3;            // 4 N-waves

  // staging: thread t covers (row = t>>2 within 128-row half, slot = (t&3)*8)
  const size_t K_ = (size_t)K;
  const uint16_t* gA = A + (size_t)(tm * BM + (tid >> 2)) * K_ + (tid & 3) * 8;
  const uint16_t* gB = B + (size_t)(tn * BN + (tid >> 2)) * K_ + (tid & 3) * 8;
  const size_t halfs = 128 * K_;     // +128 rows (second half-tile)
  const int stageBase = wid * 1024;  // wave-uniform byte offset inside half

  const int nt = K / BK;             // 64

  // fragment read offsets (bytes; tile row stride = 64 B)
  const int rd   = (lane & 15) * 64 + (lane >> 4) * 16;
  const int aoff = wm * 8192 + rd;   // + r*1024 per m-frag
  const int boff = wn * 4096 + rd;   // + n*1024 per n-frag

  f32x4 acc[8][4];
  #pragma unroll
  for (int r = 0; r < 8; ++r)
    #pragma unroll
    for (int n = 0; n < 4; ++n)
      acc[r][n] = (f32x4){0.f, 0.f, 0.f, 0.f};

#define STAGE256(b, koff)                                                     \
  { char* d = lds + (b) * 32768 + stageBase;                                  \
    GLOAD16(gA + (koff),          d);                                         \
    GLOAD16(gA + halfs + (koff),  d + 8192);                                  \
    GLOAD16(gB + (koff),          d + 16384);                                 \
    GLOAD16(gB + halfs + (koff),  d + 24576); }

  STAGE256(0, 0); STAGE256(1, 32); STAGE256(2, 64);

  for (int t = 0; t < nt; ++t) {
    const int rem = nt - 1 - t;
    if (rem >= 2)      asm volatile("s_waitcnt vmcnt(8)" ::: "memory");
    else if (rem == 1) asm volatile("s_waitcnt vmcnt(4)" ::: "memory");
    else               asm volatile("s_waitcnt vmcnt(0)" ::: "memory");
    asm volatile("s_barrier" ::: "memory");
    if (t + 3 < nt) STAGE256((t + 3) & 3, (t + 3) * BK);

    const char* bA = lds + (t & 3) * 32768;
    const char* bB = bA + 16384;
    bf16x8 bF[4], aF[8];
    #pragma unroll
    for (int n = 0; n < 4; ++n)
      bF[n] = *reinterpret_cast<const bf16x8*>(bB + boff + n * 1024);
    #pragma unroll
    for (int r = 0; r < 8; ++r)
      aF[r] = *reinterpret_cast<const bf16x8*>(bA + aoff + r * 1024);
    #pragma unroll
    for (int r = 0; r < 8; ++r)
      #pragma unroll
      for (int n = 0; n < 4; ++n)
        acc[r][n] = __builtin_amdgcn_mfma_f32_16x16x32_bf16(aF[r], bF[n],
                                                            acc[r][n], 0, 0, 0);
  }
#undef STAGE256

  // epilogue (m89-verified C/D layout)
  const int r0 = tm * BM + wm * 128 + (lane >> 4) * 4;
  const int c0 = tn * BN + wn * 64 + (lane & 15);
  #pragma unroll
  for (int r = 0; r < 8; ++r) {
    #pragma unroll
    for (int n = 0; n < 4; ++n) {
      const int c = c0 + n * 16;
      if (c < Nout) {
        const float bv = bias ? bias[c] : 0.f;
        #pragma unroll
        for (int j = 0; j < 4; ++j)
          C[(size_t)(r0 + r * 16 + j) * Nout + c] = acc[r][n][j] + bv;
      }
    }
  }
}

// ---------------- LayerNorm (adds b1), fp32 in -> bf16 out ------------------
__global__ __launch_bounds__(256) void ln_bf16(
    const float* __restrict__ h, const float* __restrict__ b1,
    const float* __restrict__ gamma, const float* __restrict__ beta,
    uint16_t* __restrict__ out)
{
  constexpr int D = 2048;
  const int row = blockIdx.x;
  const int tid = threadIdx.x;
  const float* hp = h + (size_t)row * D + tid * 8;
  float v[8];
  {
    float4 a0 = *reinterpret_cast<const float4*>(hp);
    float4 a1 = *reinterpret_cast<const float4*>(hp + 4);
    float4 c0 = *reinterpret_cast<const float4*>(b1 + tid * 8);
    float4 c1 = *reinterpret_cast<const float4*>(b1 + tid * 8 + 4);
    v[0] = a0.x + c0.x; v[1] = a0.y + c0.y; v[2] = a0.z + c0.z; v[3] = a0.w + c0.w;
    v[4] = a1.x + c1.x; v[5] = a1.y + c1.y; v[6] = a1.z + c1.z; v[7] = a1.w + c1.w;
  }
  float s = 0.f, q = 0.f;
  #pragma unroll
  for (int i = 0; i < 8; ++i) { s += v[i]; q += v[i] * v[i]; }
  #pragma unroll
  for (int off = 32; off > 0; off >>= 1) {
    s += __shfl_down(s, off);
    q += __shfl_down(q, off);
  }
  __shared__ float red[8];
  const int wid = tid >> 6, lane = tid & 63;
  if (lane == 0) { red[wid] = s; red[4 + wid] = q; }
  __syncthreads();
  s = red[0] + red[1] + red[2] + red[3];
  q = red[4] + red[5] + red[6] + red[7];
  const float mu = s * (1.f / D);
  const float rs = rsqrtf(q * (1.f / D) - mu * mu + 1e-5f);
  float4 g0 = *reinterpret_cast<const float4*>(gamma + tid * 8);
  float4 g1 = *reinterpret_cast<const float4*>(gamma + tid * 8 + 4);
  float4 e0 = *reinterpret_cast<const float4*>(beta + tid * 8);
  float4 e1 = *reinterpret_cast<const float4*>(beta + tid * 8 + 4);
  const float g[8] = {g0.x, g0.y, g0.z, g0.w, g1.x, g1.y, g1.z, g1.w};
  const float e[8] = {e0.x, e0.y, e0.z, e0.w, e1.x, e1.y, e1.z, e1.w};
  uint32_t w[4];
  #pragma unroll
  for (int i = 0; i < 4; ++i) {
    float y0 = (v[2 * i]     - mu) * rs * g[2 * i]     + e[2 * i];
    float y1 = (v[2 * i + 1] - mu) * rs * g[2 * i + 1] + e[2 * i + 1];
    w[i] = (uint32_t)f2bf(y0) | ((uint32_t)f2bf(y1) << 16);
  }
  uint4 o; o.x = w[0]; o.y = w[1]; o.z = w[2]; o.w = w[3];
  reinterpret_cast<uint4*>(out + (size_t)row * D)[tid] = o;
}

// ---------------- launch ----------------------------------------------------
extern "C" void kernel_launch(void* const* d_in, const int* in_sizes, int n_in,
                              void* d_out, int out_size, void* d_ws, size_t ws_size,
                              hipStream_t stream) {
  (void)in_sizes; (void)n_in; (void)out_size; (void)ws_size;
  const float* x     = (const float*)d_in[0];
  const float* w1    = (const float*)d_in[1];
  const float* b1    = (const float*)d_in[2];
  const float* gamma = (const float*)d_in[3];
  const float* beta  = (const float*)d_in[4];
  const float* w3    = (const float*)d_in[5];
  const float* b3    = (const float*)d_in[6];
  float* out = (float*)d_out;

  const int N = 4096, D = 2048, V = 30000, Vp = 30208;  // Vp % 256 == 0

  // ws layout (bytes). w3b aliases h/xb/w1b, which are dead once it is written
  // (cvt_pad launches AFTER GEMM1+LN). Total footprint 142 MiB.
  char* ws = (char*)d_ws;
  uint16_t* hnb = (uint16_t*)(ws);                    // [0,16) MiB
  float*    h   = (float*)   (ws + (16u << 20));      // [16,48) MiB (dead after LN)
  uint16_t* xb  = (uint16_t*)(ws + (48u << 20));      // [48,64) MiB (dead after GEMM1)
  uint16_t* w1b = (uint16_t*)(ws + (64u << 20));      // [64,72) MiB (dead after GEMM1)
  uint16_t* w3b = (uint16_t*)(ws + (24u << 20));      // [24,142) MiB, overlaps the dead ones

  hipLaunchKernelGGL(cvt_bf16, dim3(1024), dim3(256), 0, stream,
                     x, xb, (size_t)N * D / 8);
  hipLaunchKernelGGL(cvt_bf16, dim3(512), dim3(256), 0, stream,
                     w1, w1b, (size_t)D * D / 8);
  // GEMM1: h = x @ w1^T (b1 folded into LN) -- old proven 128^2 kernel
  hipLaunchKernelGGL(gemm_bt_bf16, dim3((N / 128) * (D / 128)), dim3(256), 0, stream,
                     xb, w1b, h, (const float*)nullptr, N, D, D, D);
  hipLaunchKernelGGL(ln_bf16, dim3(N), dim3(256), 0, stream,
                     h, b1, gamma, beta, hnb);
  // convert w3 AFTER LN so w3b can alias h/xb/w1b
  hipLaunchKernelGGL(cvt_bf16_pad, dim3(2048), dim3(256), 0, stream,
                     w3, w3b, V, (size_t)Vp * D / 8);
  // GEMM2: out = hn @ w3^T + b3 -- new 256^2 pipelined kernel (static 128 KiB LDS)
  hipLaunchKernelGGL(gemm_bt_256, dim3((N / 256) * (Vp / 256)), dim3(512), 0, stream,
                     hnb, w3b, out, b3, N, Vp, D, V);
}